// Round 4
// baseline (175.035 us; speedup 1.0000x reference)
//
#include <hip/hip_runtime.h>
#include <hip/hip_cooperative_groups.h>

namespace cg = cooperative_groups;

// out[b] = Q[b] @ (K[b]^T @ V[b]) / 8      (softmax in ref is dead code)
// B=8, S=2048, D=128, fp32 in/out. Single cooperative kernel, 3 phases:
//   A: P[b][ch] (bf16) = K_chunk^T @ V_chunk   (LDS-transposed, MFMA)
//   B: MT[b][c][d] (bf16) = (1/8) sum_ch P     (transposed for C's B-frags)
//   C: out[b] = Q[b] @ M[b]                     (MFMA, MT k-contiguous)

#define B 8
#define S 2048
#define D 128
#define CH 64          // s-chunks per batch
#define SC 32          // rows per chunk
#define NBLK (B * CH)  // 512 blocks, 2 per CU

typedef __attribute__((ext_vector_type(8))) short short8;
typedef __attribute__((ext_vector_type(4))) float f32x4;

static __device__ __forceinline__ short f2bf(float f) {
    union { float f; unsigned u; } x; x.f = f;
    unsigned r = x.u + 0x7FFF + ((x.u >> 16) & 1);   // RNE
    return (short)(r >> 16);
}
static __device__ __forceinline__ float bf2f(unsigned short s) {
    union { unsigned u; float f; } x; x.u = ((unsigned)s) << 16;
    return x.f;
}

__global__ __launch_bounds__(256, 2) void fused_qktv(
    const float* __restrict__ Q, const float* __restrict__ K,
    const float* __restrict__ V, unsigned short* __restrict__ P,
    unsigned short* __restrict__ MT, float* __restrict__ Out)
{
    cg::grid_group grid = cg::this_grid();

    int blk = blockIdx.x, tid = threadIdx.x;
    int w = tid >> 6, l = tid & 63;
    int lr = l & 15, lg = l >> 4;

    __shared__ float Ks[SC * D];      // 16 KB, swizzled
    __shared__ float Vs[SC * D];      // 16 KB

    // ---------------- Phase A: K_chunk^T @ V_chunk -> P (bf16) -------------
    {
        int b = blk >> 6, ch = blk & 63;
        const float* Kb = K + ((size_t)b * S + (size_t)ch * SC) * D;
        const float* Vb = V + ((size_t)b * S + (size_t)ch * SC) * D;

#pragma unroll
        for (int it = 0; it < 4; ++it) {
            int e = it * 1024 + tid * 4;          // f32 index in 32x128 chunk
            int s = e >> 7, d = e & 127;
            int d2 = d ^ (((s >> 3) & 1) << 4);   // XOR-swizzle
            *(float4*)&Ks[s * D + d2] = *(const float4*)&Kb[e];
            *(float4*)&Vs[s * D + d2] = *(const float4*)&Vb[e];
        }
        __syncthreads();

        int dr0 = (w >> 1) * 64;      // output row quadrant (d)
        int cc0 = (w & 1) * 64;       // output col quadrant (c)
        int sw = (lg & 1) << 4;       // per-lane constant swizzle

        f32x4 acc[4][4];
#pragma unroll
        for (int i = 0; i < 4; i++)
#pragma unroll
            for (int j = 0; j < 4; j++) acc[i][j] = (f32x4)0.f;

        short8 af[4], bv[4];
#pragma unroll
        for (int fi = 0; fi < 4; ++fi) {          // A = K columns
            int d = (dr0 + fi * 16 + lr) ^ sw;
            short8 t;
#pragma unroll
            for (int j = 0; j < 8; ++j) t[j] = f2bf(Ks[(lg * 8 + j) * D + d]);
            af[fi] = t;
        }
#pragma unroll
        for (int fj = 0; fj < 4; ++fj) {          // B = V columns
            int c = (cc0 + fj * 16 + lr) ^ sw;
            short8 t;
#pragma unroll
            for (int j = 0; j < 8; ++j) t[j] = f2bf(Vs[(lg * 8 + j) * D + c]);
            bv[fj] = t;
        }
#pragma unroll
        for (int fi = 0; fi < 4; ++fi)
#pragma unroll
            for (int fj = 0; fj < 4; ++fj)
                acc[fi][fj] = __builtin_amdgcn_mfma_f32_16x16x32_bf16(
                    af[fi], bv[fj], acc[fi][fj], 0, 0, 0);

        unsigned short* Pb = P + (size_t)blk * D * D;
#pragma unroll
        for (int fi = 0; fi < 4; ++fi)
#pragma unroll
            for (int fj = 0; fj < 4; ++fj)
#pragma unroll
                for (int j = 0; j < 4; ++j) {
                    int row = dr0 + fi * 16 + lg * 4 + j;
                    int col = cc0 + fj * 16 + lr;
                    Pb[row * D + col] = (unsigned short)f2bf(acc[fi][fj][j]);
                }
    }

    grid.sync();

    // ---------------- Phase B: reduce P -> MT (bf16, transposed) -----------
    {
        int idx = blk * 256 + tid;                 // 131072 = B*D*D threads
        int b = idx >> 14, r = idx & 16383;        // r = d*128 + c
        const unsigned short* Pb = P + (size_t)(b * CH) * D * D;
        float s = 0.f;
#pragma unroll 8
        for (int cc = 0; cc < CH; ++cc)
            s += bf2f(Pb[(size_t)cc * D * D + r]);
        int d = r >> 7, c = r & 127;
        MT[(size_t)b * D * D + c * D + d] = (unsigned short)f2bf(s * 0.125f);
    }

    grid.sync();

    // ---------------- Phase C: out = Q @ M ---------------------------------
    {
        int b = blk >> 6, t = blk & 63;            // 64 row-tiles of 32
        int r0 = t * 32 + (w >> 1) * 16;           // wave rows
        int c0 = (w & 1) * 64;                     // wave cols

        const float* Qb = Q + ((size_t)b * S + r0) * D;
        const unsigned short* Mb = MT + (size_t)b * D * D;

        f32x4 acc[4];
#pragma unroll
        for (int j = 0; j < 4; j++) acc[j] = (f32x4)0.f;

#pragma unroll
        for (int ks = 0; ks < 4; ++ks) {
            int k0 = ks * 32 + lg * 8;
            const float* qp = Qb + (size_t)lr * D + k0;
            float4 q0 = *(const float4*)qp;
            float4 q1 = *(const float4*)(qp + 4);
            short8 a;
            a[0] = f2bf(q0.x); a[1] = f2bf(q0.y); a[2] = f2bf(q0.z); a[3] = f2bf(q0.w);
            a[4] = f2bf(q1.x); a[5] = f2bf(q1.y); a[6] = f2bf(q1.z); a[7] = f2bf(q1.w);
#pragma unroll
            for (int fj = 0; fj < 4; ++fj) {
                short8 bb = *(const short8*)(Mb + (size_t)(c0 + fj * 16 + lr) * D + k0);
                acc[fj] = __builtin_amdgcn_mfma_f32_16x16x32_bf16(a, bb, acc[fj], 0, 0, 0);
            }
        }

        float* Ob = Out + ((size_t)b * S + r0) * D;
#pragma unroll
        for (int fj = 0; fj < 4; ++fj)
#pragma unroll
            for (int j = 0; j < 4; ++j)
                Ob[(size_t)(lg * 4 + j) * D + c0 + fj * 16 + lr] = acc[fj][j];
    }
}

extern "C" void kernel_launch(void* const* d_in, const int* in_sizes, int n_in,
                              void* d_out, int out_size, void* d_ws, size_t ws_size,
                              hipStream_t stream)
{
    const float* q = (const float*)d_in[0];
    const float* k = (const float*)d_in[1];
    const float* v = (const float*)d_in[2];
    float* out = (float*)d_out;

    unsigned short* P  = (unsigned short*)d_ws;            // 16.8 MB
    unsigned short* MT = P + (size_t)NBLK * D * D;         // 256 KB

    void* args[] = { (void*)&q, (void*)&k, (void*)&v,
                     (void*)&P, (void*)&MT, (void*)&out };
    hipLaunchCooperativeKernel((void*)fused_qktv, dim3(NBLK), dim3(256),
                               args, 0, stream);
}

// Round 5
// 24.375 us; speedup vs baseline: 7.1810x; 7.1810x over previous
//
#include <hip/hip_runtime.h>
#include <hip/hip_bf16.h>

// out[b] = Q[b] @ (K[b]^T @ V[b]) / 8      (softmax in ref is dead code)
// B=8, S=2048, D=128, fp32 in/out. bf16 MFMA, 3 kernels:
//  S1: P[b][ch] = K_chunk^T @ V_chunk (bf16 partials, CH=32, 512 blocks,
//      each block one 64x128 d-half -> 2 blocks/CU, 2 waves/SIMD)
//  S2: MT[b][c][d] = (1/8) sum_ch P   (transposed so S3 B-frags are k-contig)
//  S3: out = Q @ M (512 blocks, per-wave 16x64 tile)

#define B 8
#define S 2048
#define D 128
#define CH 32          // s-chunks per batch
#define SC 64          // rows per chunk

typedef __attribute__((ext_vector_type(8))) short short8;
typedef __attribute__((ext_vector_type(4))) float f32x4;

static __device__ __forceinline__ short f2bf(float f) {
    __hip_bfloat16 h = __float2bfloat16(f);      // RNE; compiler packs v_cvt_pk
    union { __hip_bfloat16 h; short s; } u; u.h = h;
    return u.s;
}
static __device__ __forceinline__ float bf2f(unsigned short s) {
    union { unsigned u; float f; } x; x.u = ((unsigned)s) << 16;
    return x.f;
}

// ---- Stage 1: P[b][ch] (bf16) = K_chunk^T @ V_chunk ------------------------
__global__ __launch_bounds__(256) void s1_ktv(
    const float* __restrict__ K, const float* __restrict__ V,
    unsigned short* __restrict__ P)
{
    int blk = blockIdx.x;                     // 512
    int b = blk >> 6, rem = blk & 63;
    int ch = rem >> 1, h = rem & 1;           // d-half of the 128x128 output
    const float* Kb = K + ((size_t)b * S + (size_t)ch * SC) * D;
    const float* Vb = V + ((size_t)b * S + (size_t)ch * SC) * D;

    int tid = threadIdx.x;
    int w = tid >> 6, l = tid & 63;
    int lr = l & 15, lg = l >> 4;
    int dr0 = h * 64 + (w >> 1) * 32;         // output rows (K columns)
    int cc0 = (w & 1) * 64;                   // output cols (V columns)

    f32x4 acc[2][4];
#pragma unroll
    for (int i = 0; i < 2; i++)
#pragma unroll
        for (int j = 0; j < 4; j++) acc[i][j] = (f32x4)0.f;

#pragma unroll
    for (int ks = 0; ks < 2; ++ks) {
        int sb = ks * 32 + lg * 8;            // this lane's 8 s-rows
        short8 af[2], bv[4];
#pragma unroll
        for (int fi = 0; fi < 2; ++fi) {      // A = K columns (K^T rows)
            const float* kp = Kb + (size_t)sb * D + dr0 + fi * 16 + lr;
            float t[8];
#pragma unroll
            for (int i = 0; i < 8; ++i) t[i] = kp[(size_t)i * D];
            short8 s8;
#pragma unroll
            for (int i = 0; i < 8; ++i) s8[i] = f2bf(t[i]);
            af[fi] = s8;
        }
#pragma unroll
        for (int fj = 0; fj < 4; ++fj) {      // B = V columns
            const float* vp = Vb + (size_t)sb * D + cc0 + fj * 16 + lr;
            float t[8];
#pragma unroll
            for (int i = 0; i < 8; ++i) t[i] = vp[(size_t)i * D];
            short8 s8;
#pragma unroll
            for (int i = 0; i < 8; ++i) s8[i] = f2bf(t[i]);
            bv[fj] = s8;
        }
#pragma unroll
        for (int fi = 0; fi < 2; ++fi)
#pragma unroll
            for (int fj = 0; fj < 4; ++fj)
                acc[fi][fj] = __builtin_amdgcn_mfma_f32_16x16x32_bf16(
                    af[fi], bv[fj], acc[fi][fj], 0, 0, 0);
    }

    unsigned short* Pb = P + (size_t)(b * CH + ch) * D * D;
#pragma unroll
    for (int fi = 0; fi < 2; ++fi)
#pragma unroll
        for (int fj = 0; fj < 4; ++fj)
#pragma unroll
            for (int j = 0; j < 4; ++j) {
                int row = dr0 + fi * 16 + lg * 4 + j;
                int col = cc0 + fj * 16 + lr;
                Pb[row * D + col] = (unsigned short)f2bf(acc[fi][fj][j]);
            }
}

// ---- Stage 2: MT[b][c][d] (bf16) = (1/8) * sum_ch P[b][ch][d][c] ----------
__global__ __launch_bounds__(256) void s2_reduce(
    const unsigned short* __restrict__ P, unsigned short* __restrict__ MT)
{
    int idx = blockIdx.x * 256 + threadIdx.x;   // 65536 threads, 2 elems each
    int i0 = idx * 2;
    int b = i0 >> 14;
    int r = i0 & 16383;                          // r = d*128 + c, c even
    const unsigned short* Pb = P + (size_t)(b * CH) * D * D;
    float s0 = 0.f, s1 = 0.f;
#pragma unroll 8
    for (int cc = 0; cc < CH; ++cc) {
        unsigned pair = *(const unsigned*)(Pb + (size_t)cc * D * D + r);
        s0 += bf2f((unsigned short)(pair & 0xFFFF));
        s1 += bf2f((unsigned short)(pair >> 16));
    }
    int d = r >> 7, c = r & 127;
    unsigned short* Mb = MT + (size_t)b * D * D;
    Mb[c * D + d]       = (unsigned short)f2bf(s0 * 0.125f);
    Mb[(c + 1) * D + d] = (unsigned short)f2bf(s1 * 0.125f);
}

// ---- Stage 3: out[b] = Q[b] @ M[b]  (per-wave 16x64 tile) ------------------
__global__ __launch_bounds__(256) void s3_qm(
    const float* __restrict__ Q, const unsigned short* __restrict__ MT,
    float* __restrict__ Out)
{
    int blk = blockIdx.x;                  // 512
    int b = blk >> 6, t = blk & 63;        // 64 row-tiles of 32
    int tid = threadIdx.x;
    int w = tid >> 6, l = tid & 63;
    int lr = l & 15, lg = l >> 4;
    int r0 = t * 32 + (w >> 1) * 16;       // wave rows
    int c0 = (w & 1) * 64;                 // wave cols

    const float* Qb = Q + ((size_t)b * S + r0) * D;
    const unsigned short* Mb = MT + (size_t)b * D * D;

    f32x4 acc[4];
#pragma unroll
    for (int j = 0; j < 4; j++) acc[j] = (f32x4)0.f;

#pragma unroll
    for (int ks = 0; ks < 4; ++ks) {
        int k0 = ks * 32 + lg * 8;
        const float* qp = Qb + (size_t)lr * D + k0;
        float4 q0 = *(const float4*)qp;
        float4 q1 = *(const float4*)(qp + 4);
        short8 a;
        a[0] = f2bf(q0.x); a[1] = f2bf(q0.y); a[2] = f2bf(q0.z); a[3] = f2bf(q0.w);
        a[4] = f2bf(q1.x); a[5] = f2bf(q1.y); a[6] = f2bf(q1.z); a[7] = f2bf(q1.w);
#pragma unroll
        for (int fj = 0; fj < 4; ++fj) {
            short8 bb = *(const short8*)(Mb + (size_t)(c0 + fj * 16 + lr) * D + k0);
            acc[fj] = __builtin_amdgcn_mfma_f32_16x16x32_bf16(a, bb, acc[fj], 0, 0, 0);
        }
    }

    float* Ob = Out + ((size_t)b * S + r0) * D;
#pragma unroll
    for (int fj = 0; fj < 4; ++fj)
#pragma unroll
        for (int j = 0; j < 4; ++j)
            Ob[(size_t)(lg * 4 + j) * D + c0 + fj * 16 + lr] = acc[fj][j];
}

extern "C" void kernel_launch(void* const* d_in, const int* in_sizes, int n_in,
                              void* d_out, int out_size, void* d_ws, size_t ws_size,
                              hipStream_t stream)
{
    const float* q = (const float*)d_in[0];
    const float* k = (const float*)d_in[1];
    const float* v = (const float*)d_in[2];
    float* out = (float*)d_out;

    unsigned short* P  = (unsigned short*)d_ws;            // 8.4 MB
    unsigned short* MT = P + (size_t)B * CH * D * D;       // 256 KB

    s1_ktv<<<B * CH * 2, 256, 0, stream>>>(k, v, P);
    s2_reduce<<<(B * D * D / 2) / 256, 256, 0, stream>>>(P, MT);
    s3_qm<<<B * 64, 256, 0, stream>>>(q, MT, out);
}